// Round 3
// baseline (29845.230 us; speedup 1.0000x reference)
//
#include <hip/hip_runtime.h>

// LSTM T=1024 B=16 I=H=1024 L=2. Inputs/outputs are FLOAT32 (per reference);
// internal compute uses bf16 MFMA (test threshold is bf16-level: 2.125e-2).
// d_in: x, Wih_0, bih_0, Whh_0, bhh_0, Wih_1, bih_1, Whh_1, bhh_1 (f32)
// d_out (f32): out1 [1024,16,1024] | next_h [2,16,1024] | next_c [2,16,1024]

#define T_STEPS 1024
#define NBLK 64      // persistent blocks in scan (1 per CU slice of gate cols)
#define TQ 8         // t-chunks for gx gemm grid

typedef unsigned short u16;
typedef __attribute__((ext_vector_type(8))) __bf16 bf16x8;      // 8 bf16 = 4 VGPR
typedef __attribute__((ext_vector_type(4))) float float4v;      // MFMA C/D + f32 loads
typedef __attribute__((ext_vector_type(4))) unsigned short ushort4v;
typedef __attribute__((ext_vector_type(8))) unsigned short ushort8;

__device__ __forceinline__ float bf2f(u16 h) {
    unsigned u = ((unsigned)h) << 16;
    return __builtin_bit_cast(float, u);
}
__device__ __forceinline__ u16 f2bf(float f) {
    unsigned u = __builtin_bit_cast(unsigned, f);
    u += 0x7fff + ((u >> 16) & 1);   // RNE
    return (u16)(u >> 16);
}

// D = A*B + C, 16x16x32 bf16. A: lane L holds A[L%16][(L/16)*8+j].
// B: lane L holds B[(L/16)*8+j][L%16]. C/D: row=(L/16)*4+r, col=L%16.
__device__ __forceinline__ float4v mfma16(bf16x8 a, bf16x8 b, float4v c) {
    return __builtin_amdgcn_mfma_f32_16x16x32_bf16(a, b, c, 0, 0, 0);
}

// ---------------------------------------------------------------- init
__global__ void init_zero(unsigned* __restrict__ cnt,   // 2*1025
                          unsigned* __restrict__ h0,    // 8192  (hist0 slot 0)
                          unsigned* __restrict__ h1) {  // 16384 (hist1 both slots)
    int i = blockIdx.x * 256 + threadIdx.x;
    const int total = 2050 + 8192 + 16384;
    for (int k = i; k < total; k += 64 * 256) {
        if (k < 2050) cnt[k] = 0u;
        else if (k < 2050 + 8192) h0[k - 2050] = 0u;
        else h1[k - 2050 - 8192] = 0u;
    }
}

// ---------------------------------------------------------------- pack
// f32 source -> bf16 MFMA-fragment-packed dest.
// dst[tile][kc(32)][lane(64)][8] = src[rowbase(tile)+lane%16][kc*32+(lane/16)*8 + j]
// mode 0 (x):  rowbase = tile*16                         (tile = t, 1024 tiles)
// mode 1 (W):  rowbase = (tile&3)*1024 + (tile>>2)*16    (tile = blk*4+w, 256 tiles)
__global__ void pack_tiles(const float* __restrict__ src, u16* __restrict__ dst, int mode) {
    int tile = blockIdx.x, tid = threadIdx.x;
    int rowbase = (mode == 0) ? (tile << 4) : (((tile & 3) << 10) + ((tile >> 2) << 4));
    ushort8* d = (ushort8*)dst;
#pragma unroll
    for (int it = 0; it < 8; ++it) {
        int c = tid + it * 256;
        int kc = c >> 6, lane = c & 63;
        const float4v* s4 = (const float4v*)(src + (((long)(rowbase + (lane & 15))) << 10)
                                                 + (kc << 5) + ((lane >> 4) << 3));
        float4v lo = s4[0], hi = s4[1];
        ushort8 o;
        o[0] = f2bf(lo[0]); o[1] = f2bf(lo[1]); o[2] = f2bf(lo[2]); o[3] = f2bf(lo[3]);
        o[4] = f2bf(hi[0]); o[5] = f2bf(hi[1]); o[6] = f2bf(hi[2]); o[7] = f2bf(hi[3]);
        d[tile * 2048 + c] = o;
    }
}

// ---------------------------------------------------------------- gx gemm
// gx[t][blk][w][L][r] (bf16, C-frag order) = (Apack[t] @ W^T)[tile] + bih + bhh
__global__ __launch_bounds__(256, 1) void gx_gemm(
        const bf16x8* __restrict__ ap,   // [t][kc*64+L] A-frag packed
        const bf16x8* __restrict__ wp,   // [td][kc*64+L] B-frag packed
        const float* __restrict__ bih, const float* __restrict__ bhh,
        u16* __restrict__ gx) {
    int blk = blockIdx.x, tq = blockIdx.y;
    int tid = threadIdx.x, w = tid >> 6, L = tid & 63;
    int td = blk * 4 + w;
    int gc = (w << 10) + (blk << 4) + (L & 15);
    float bsum = bih[gc] + bhh[gc];

    bf16x8 wf[32];
    const bf16x8* wpt = wp + td * 2048;
#pragma unroll
    for (int kc = 0; kc < 32; ++kc) wf[kc] = wpt[kc * 64 + L];

    const int tch = T_STEPS / TQ;
    for (int tt = 0; tt < tch; ++tt) {
        int t = tq * tch + tt;
        const bf16x8* at = ap + t * 2048;
        float4v a0 = {0.f, 0.f, 0.f, 0.f}, a1 = {0.f, 0.f, 0.f, 0.f};
#pragma unroll
        for (int kc = 0; kc < 16; ++kc) {
            a0 = mfma16(at[(2 * kc) * 64 + L], wf[2 * kc], a0);
            a1 = mfma16(at[(2 * kc + 1) * 64 + L], wf[2 * kc + 1], a1);
        }
        ushort4v o;
#pragma unroll
        for (int r = 0; r < 4; ++r) o[r] = f2bf(a0[r] + a1[r] + bsum);
        ((ushort4v*)gx)[((t * 64 + blk) * 4 + w) * 64 + L] = o;
    }
}

// ---------------------------------------------------------------- scan
__global__ __launch_bounds__(256, 1) void lstm_scan(
        const u16* __restrict__ gx,      // C-frag packed gates_x (+both biases)
        const bf16x8* __restrict__ wp,   // Whh B-frag packed
        bf16x8* hist,                    // slots of 2048 bf16x8 (32KB), A-frag layout
        unsigned* cnt,                   // T+1 counters, pre-zeroed
        int histmask,                    // 0x7fffffff (full history) or 1 (ping-pong)
        float* out1,                     // nullptr for layer 0
        float* finalH, float* finalC) {
    int blk = blockIdx.x;
    int tid = threadIdx.x, w = tid >> 6, L = tid & 63;
    int td = blk * 4 + w;

    bf16x8 wf[32];
    const bf16x8* wpt = wp + td * 2048;
#pragma unroll
    for (int kc = 0; kc < 32; ++kc) wf[kc] = wpt[kc * 64 + L];

    int m = tid >> 4, j = tid & 15;          // this thread's (batch, local h col)
    int hcol = (blk << 4) + j;
    int Lc = ((m >> 2) << 4) | j, rr = m & 3; // C-frag position of (m, j)
    // A-frag position of h[m][hcol] for the hist write:
    int kcw = hcol >> 5, laneg = (hcol >> 3) & 3, jj = hcol & 7;
    int hwoff = (kcw * 64 + (m + (laneg << 4))) * 8 + jj;

    float c = 0.f;
    __shared__ float4v lds_g[4][64];

    for (int t = 0; t < T_STEPS; ++t) {
        if (t > 0) {
            if (tid == 0) {
                while (__hip_atomic_load(&cnt[t], __ATOMIC_ACQUIRE,
                                         __HIP_MEMORY_SCOPE_AGENT) < (unsigned)NBLK)
                    __builtin_amdgcn_s_sleep(1);
            }
            __syncthreads();
            __threadfence();   // acquire side: invalidate caches before reading fresh h
        }
        const bf16x8* hp = hist + (t & histmask) * 2048;
        ushort4v gxv = ((const ushort4v*)gx)[((t * 64 + blk) * 4 + w) * 64 + L];
        float4v a0 = {0.f, 0.f, 0.f, 0.f}, a1 = {0.f, 0.f, 0.f, 0.f};
#pragma unroll
        for (int kc = 0; kc < 16; ++kc) {
            a0 = mfma16(hp[(2 * kc) * 64 + L], wf[2 * kc], a0);
            a1 = mfma16(hp[(2 * kc + 1) * 64 + L], wf[2 * kc + 1], a1);
        }
        float4v g4;
#pragma unroll
        for (int r = 0; r < 4; ++r) g4[r] = a0[r] + a1[r] + bf2f(gxv[r]);
        lds_g[w][L] = g4;
        __syncthreads();

        float gi = lds_g[0][Lc][rr], gf = lds_g[1][Lc][rr];
        float gg = lds_g[2][Lc][rr], go = lds_g[3][Lc][rr];
        float iv = 1.f / (1.f + __expf(-gi));
        float fv = 1.f / (1.f + __expf(-gf));
        float gv = 1.f - 2.f / (1.f + __expf(2.f * gg));
        float ov = 1.f / (1.f + __expf(-go));
        c = fv * c + iv * gv;
        float h = ov * (1.f - 2.f / (1.f + __expf(2.f * c)));
        u16 hb = f2bf(h);

        ((u16*)hist)[((t + 1) & histmask) * 16384 + hwoff] = hb;
        if (out1) out1[(t << 14) + (m << 10) + hcol] = h;
        if (t == T_STEPS - 1) {
            finalH[(m << 10) + hcol] = h;
            finalC[(m << 10) + hcol] = c;
        }
        __threadfence();   // release side: push h to agent scope
        __syncthreads();
        if (tid == 0)
            __hip_atomic_fetch_add(&cnt[t + 1], 1u, __ATOMIC_RELEASE,
                                   __HIP_MEMORY_SCOPE_AGENT);
    }
}

// ---------------------------------------------------------------- launch
extern "C" void kernel_launch(void* const* d_in, const int* in_sizes, int n_in,
                              void* d_out, int out_size, void* d_ws, size_t ws_size,
                              hipStream_t stream) {
    const float* x    = (const float*)d_in[0];
    const float* Wih0 = (const float*)d_in[1];
    const float* bih0 = (const float*)d_in[2];
    const float* Whh0 = (const float*)d_in[3];
    const float* bhh0 = (const float*)d_in[4];
    const float* Wih1 = (const float*)d_in[5];
    const float* bih1 = (const float*)d_in[6];
    const float* Whh1 = (const float*)d_in[7];
    const float* bhh1 = (const float*)d_in[8];
    float* out = (float*)d_out;

    char* ws = (char*)d_ws;
    // ws layout (bytes):
    u16* wpIh0 = (u16*)(ws + 0);            //  8,388,608
    u16* wpHh0 = (u16*)(ws + 8388608);      //  8,388,608
    u16* wpIh1 = (u16*)(ws + 16777216);     //  8,388,608
    u16* wpHh1 = (u16*)(ws + 25165824);     //  8,388,608
    u16* xpack = (u16*)(ws + 33554432);     // 33,554,432 (1024 tiles x 32KB)
    u16* hist0 = (u16*)(ws + 67108864);     // 33,587,200 (1025 slots x 32KB)
    u16* hist1 = (u16*)(ws + 100696064);    //     65,536 (2 slots ping-pong)
    u16* gxbuf = (u16*)(ws + 100761600);    // 134,217,728
    unsigned* cnt = (unsigned*)(ws + 234979328); // 8,200  -> total ~225 MiB

    init_zero<<<dim3(64), dim3(256), 0, stream>>>(cnt, (unsigned*)hist0, (unsigned*)hist1);

    pack_tiles<<<dim3(256), dim3(256), 0, stream>>>(Wih0, wpIh0, 1);
    pack_tiles<<<dim3(256), dim3(256), 0, stream>>>(Whh0, wpHh0, 1);
    pack_tiles<<<dim3(256), dim3(256), 0, stream>>>(Wih1, wpIh1, 1);
    pack_tiles<<<dim3(256), dim3(256), 0, stream>>>(Whh1, wpHh1, 1);
    pack_tiles<<<dim3(1024), dim3(256), 0, stream>>>(x, xpack, 0);

    // layer 0: gx = x @ Wih0^T + bih0 + bhh0 ; scan (full h history kept)
    gx_gemm<<<dim3(64, TQ), dim3(256), 0, stream>>>(
        (const bf16x8*)xpack, (const bf16x8*)wpIh0, bih0, bhh0, gxbuf);
    lstm_scan<<<dim3(NBLK), dim3(256), 0, stream>>>(
        gxbuf, (const bf16x8*)wpHh0, (bf16x8*)hist0, cnt, 0x7fffffff,
        (float*)nullptr, out + 16777216, out + 16777216 + 32768);

    // layer 1: gx = out0 @ Wih1^T + biases ; scan (ping-pong h, writes out1)
    gx_gemm<<<dim3(64, TQ), dim3(256), 0, stream>>>(
        ((const bf16x8*)hist0) + 2048, (const bf16x8*)wpIh1, bih1, bhh1, gxbuf);
    lstm_scan<<<dim3(NBLK), dim3(256), 0, stream>>>(
        gxbuf, (const bf16x8*)wpHh1, (bf16x8*)hist1, cnt + 1025, 1,
        out, out + 16777216 + 16384, out + 16777216 + 32768 + 16384);
}

// Round 4
// 10744.397 us; speedup vs baseline: 2.7777x; 2.7777x over previous
//
#include <hip/hip_runtime.h>

// LSTM T=1024 B=16 I=H=1024 L=2. f32 in/out, bf16 MFMA internally.
// d_in: x, Wih_0, bih_0, Whh_0, bhh_0, Wih_1, bih_1, Whh_1, bhh_1 (f32)
// d_out (f32): out1 [1024,16,1024] | next_h [2,16,1024] | next_c [2,16,1024]
//
// Scan sync design (round 3): NO __threadfence (agent fence = full L2
// wb+inv on gfx950 = 13.8us/step). Cross-block h + flags move through
// relaxed AGENT-scope atomics only (compile to sc0/sc1 cache-bypass
// accesses against the coherent LLC; no cache maintenance instructions).

#define T_STEPS 1024
#define NBLK 64      // persistent scan blocks (1/CU), 16 h-cols each
#define TQ 8         // t-chunks for gx gemm grid

typedef unsigned short u16;
typedef unsigned long long u64;
typedef __attribute__((ext_vector_type(8))) __bf16 bf16x8;      // 8 bf16 = 4 VGPR
typedef __attribute__((ext_vector_type(4))) float float4v;      // MFMA C/D + f32 loads
typedef __attribute__((ext_vector_type(4))) unsigned short ushort4v;
typedef __attribute__((ext_vector_type(8))) unsigned short ushort8;

__device__ __forceinline__ float bf2f(u16 h) {
    unsigned u = ((unsigned)h) << 16;
    return __builtin_bit_cast(float, u);
}
__device__ __forceinline__ u16 f2bf(float f) {
    unsigned u = __builtin_bit_cast(unsigned, f);
    u += 0x7fff + ((u >> 16) & 1);   // RNE
    return (u16)(u >> 16);
}

// D = A*B + C, 16x16x32 bf16. A: lane L holds A[L%16][(L/16)*8+j].
// B: lane L holds B[(L/16)*8+j][L%16]. C/D: row=(L/16)*4+r, col=L%16.
__device__ __forceinline__ float4v mfma16(bf16x8 a, bf16x8 b, float4v c) {
    return __builtin_amdgcn_mfma_f32_16x16x32_bf16(a, b, c, 0, 0, 0);
}

// ---------------------------------------------------------------- init
__global__ void init_zero(unsigned* __restrict__ flags,  // 1025*64 = 65600
                          unsigned* __restrict__ h0,     // 8192  (hist0 slot 0)
                          unsigned* __restrict__ h1) {   // 16384 (hist1 both slots)
    int i = blockIdx.x * 256 + threadIdx.x;
    const int total = 65600 + 8192 + 16384;
    for (int k = i; k < total; k += 64 * 256) {
        if (k < 65600) flags[k] = 0u;
        else if (k < 65600 + 8192) h0[k - 65600] = 0u;
        else h1[k - 65600 - 8192] = 0u;
    }
}

// ---------------------------------------------------------------- pack
// f32 source -> bf16 MFMA-fragment-packed dest.
// dst[tile][kc(32)][lane(64)][8] = src[rowbase(tile)+lane%16][kc*32+(lane/16)*8 + j]
// mode 0 (x):  rowbase = tile*16                         (tile = t, 1024 tiles)
// mode 1 (W):  rowbase = (tile&3)*1024 + (tile>>2)*16    (tile = blk*4+w, 256 tiles)
__global__ void pack_tiles(const float* __restrict__ src, u16* __restrict__ dst, int mode) {
    int tile = blockIdx.x, tid = threadIdx.x;
    int rowbase = (mode == 0) ? (tile << 4) : (((tile & 3) << 10) + ((tile >> 2) << 4));
    ushort8* d = (ushort8*)dst;
#pragma unroll
    for (int it = 0; it < 8; ++it) {
        int c = tid + it * 256;
        int kc = c >> 6, lane = c & 63;
        const float4v* s4 = (const float4v*)(src + (((long)(rowbase + (lane & 15))) << 10)
                                                 + (kc << 5) + ((lane >> 4) << 3));
        float4v lo = s4[0], hi = s4[1];
        ushort8 o;
        o[0] = f2bf(lo[0]); o[1] = f2bf(lo[1]); o[2] = f2bf(lo[2]); o[3] = f2bf(lo[3]);
        o[4] = f2bf(hi[0]); o[5] = f2bf(hi[1]); o[6] = f2bf(hi[2]); o[7] = f2bf(hi[3]);
        d[tile * 2048 + c] = o;
    }
}

// ---------------------------------------------------------------- gx gemm
// gx[t][blk][w][L][r] (bf16, C-frag order) = (Apack[t] @ W^T)[tile] + bih + bhh
__global__ __launch_bounds__(256, 1) void gx_gemm(
        const bf16x8* __restrict__ ap,   // [t][kc*64+L] A-frag packed
        const bf16x8* __restrict__ wp,   // [td][kc*64+L] B-frag packed
        const float* __restrict__ bih, const float* __restrict__ bhh,
        u16* __restrict__ gx) {
    int blk = blockIdx.x, tq = blockIdx.y;
    int tid = threadIdx.x, w = tid >> 6, L = tid & 63;
    int td = blk * 4 + w;
    int gc = (w << 10) + (blk << 4) + (L & 15);
    float bsum = bih[gc] + bhh[gc];

    bf16x8 wf[32];
    const bf16x8* wpt = wp + td * 2048;
#pragma unroll
    for (int kc = 0; kc < 32; ++kc) wf[kc] = wpt[kc * 64 + L];

    const int tch = T_STEPS / TQ;
    for (int tt = 0; tt < tch; ++tt) {
        int t = tq * tch + tt;
        const bf16x8* at = ap + t * 2048;
        float4v a0 = {0.f, 0.f, 0.f, 0.f}, a1 = {0.f, 0.f, 0.f, 0.f};
#pragma unroll
        for (int kc = 0; kc < 16; ++kc) {
            a0 = mfma16(at[(2 * kc) * 64 + L], wf[2 * kc], a0);
            a1 = mfma16(at[(2 * kc + 1) * 64 + L], wf[2 * kc + 1], a1);
        }
        ushort4v o;
#pragma unroll
        for (int r = 0; r < 4; ++r) o[r] = f2bf(a0[r] + a1[r] + bsum);
        ((ushort4v*)gx)[((t * 64 + blk) * 4 + w) * 64 + L] = o;
    }
}

// ---------------------------------------------------------------- scan
__global__ __launch_bounds__(256, 1) void lstm_scan(
        const u16* __restrict__ gx,      // C-frag packed gates_x (+both biases)
        const bf16x8* __restrict__ wp,   // Whh B-frag packed
        unsigned* histw,                 // u32 view of hist slots (8192 u32/slot)
        unsigned* flags,                 // [1025][64], monotonic layer tags
        unsigned want,                   // 1 for layer 0, 2 for layer 1
        int histmask,                    // 0x7fffffff (full history) or 1 (ping-pong)
        float* out1,                     // nullptr for layer 0
        float* finalH, float* finalC) {
    int blk = blockIdx.x;
    int tid = threadIdx.x, w = tid >> 6, L = tid & 63;
    int td = blk * 4 + w;

    bf16x8 wf[32];
    const bf16x8* wpt = wp + td * 2048;
#pragma unroll
    for (int kc = 0; kc < 32; ++kc) wf[kc] = wpt[kc * 64 + L];

    int m = tid >> 4, j = tid & 15;          // this thread's (batch, local h col)
    int hcol = (blk << 4) + j;
    int Lc = ((m >> 2) << 4) | j, rr = m & 3; // C-frag position of (m, j)
    // A-frag u32 position of paired h[m][hcol],h[m][hcol+1] (even j lanes write):
    int kcw = hcol >> 5, laneg = (hcol >> 3) & 3, jj = hcol & 7;
    int hwoff32 = ((kcw * 64 + m + (laneg << 4)) << 2) + (jj >> 1);

    float c = 0.f;
    __shared__ u64 hbuf64[4096];             // 32 KB staged h(t), slot-linear
    __shared__ float4v lds_g[4][64];
    const bf16x8* hp = (const bf16x8*)hbuf64;

    for (int t = 0; t < T_STEPS; ++t) {
        // gx load first (independent of h(t)) to hide its latency behind the poll
        ushort4v gxv = ((const ushort4v*)gx)[((t * 64 + blk) * 4 + w) * 64 + L];

        if (t > 0) {
            if (tid < 64) {   // wave 0 polls all 64 producer flags
                unsigned v;
                do {
                    v = __hip_atomic_load(&flags[t * 64 + tid], __ATOMIC_RELAXED,
                                          __HIP_MEMORY_SCOPE_AGENT);
                } while (__ballot(v >= want) != ~0ull);
            }
            __syncthreads();
        }

        // cooperative coherent load of h(t) slot (32 KB) into LDS, once per block
        {
            const u64* hsrc = (const u64*)histw + (size_t)(t & histmask) * 4096;
            u64 tmp[16];
#pragma unroll
            for (int i = 0; i < 16; ++i)
                tmp[i] = __hip_atomic_load(hsrc + (i << 8) + tid, __ATOMIC_RELAXED,
                                           __HIP_MEMORY_SCOPE_AGENT);
#pragma unroll
            for (int i = 0; i < 16; ++i) hbuf64[(i << 8) + tid] = tmp[i];
        }
        __syncthreads();

        float4v a0 = {0.f, 0.f, 0.f, 0.f}, a1 = {0.f, 0.f, 0.f, 0.f};
#pragma unroll
        for (int kc = 0; kc < 16; ++kc) {
            a0 = mfma16(hp[(2 * kc) * 64 + L], wf[2 * kc], a0);
            a1 = mfma16(hp[(2 * kc + 1) * 64 + L], wf[2 * kc + 1], a1);
        }
        float4v g4;
#pragma unroll
        for (int r = 0; r < 4; ++r) g4[r] = a0[r] + a1[r] + bf2f(gxv[r]);
        lds_g[w][L] = g4;
        __syncthreads();

        float gi = lds_g[0][Lc][rr], gf = lds_g[1][Lc][rr];
        float gg = lds_g[2][Lc][rr], go = lds_g[3][Lc][rr];
        float iv = 1.f / (1.f + __expf(-gi));
        float fv = 1.f / (1.f + __expf(-gf));
        float gv = 1.f - 2.f / (1.f + __expf(2.f * gg));
        float ov = 1.f / (1.f + __expf(-go));
        c = fv * c + iv * gv;
        float h = ov * (1.f - 2.f / (1.f + __expf(2.f * c)));
        unsigned hb = f2bf(h);

        // paired u32 coherent store of h(t+1) in A-frag layout
        unsigned other = (unsigned)__shfl_xor((int)hb, 1);
        if (!(tid & 1)) {
            unsigned val = hb | (other << 16);
            __hip_atomic_store(histw + (size_t)((t + 1) & histmask) * 8192 + hwoff32,
                               val, __ATOMIC_RELAXED, __HIP_MEMORY_SCOPE_AGENT);
        }
        if (out1) out1[(t << 14) + (m << 10) + hcol] = h;
        if (t == T_STEPS - 1) {
            finalH[(m << 10) + hcol] = h;
            finalC[(m << 10) + hcol] = c;
        }
        __builtin_amdgcn_s_waitcnt(0);   // own h stores acked at coherent point
        __syncthreads();                 // whole block's stores done
        if (tid == 0)
            __hip_atomic_store(&flags[(t + 1) * 64 + blk], want,
                               __ATOMIC_RELAXED, __HIP_MEMORY_SCOPE_AGENT);
    }
}

// ---------------------------------------------------------------- launch
extern "C" void kernel_launch(void* const* d_in, const int* in_sizes, int n_in,
                              void* d_out, int out_size, void* d_ws, size_t ws_size,
                              hipStream_t stream) {
    const float* x    = (const float*)d_in[0];
    const float* Wih0 = (const float*)d_in[1];
    const float* bih0 = (const float*)d_in[2];
    const float* Whh0 = (const float*)d_in[3];
    const float* bhh0 = (const float*)d_in[4];
    const float* Wih1 = (const float*)d_in[5];
    const float* bih1 = (const float*)d_in[6];
    const float* Whh1 = (const float*)d_in[7];
    const float* bhh1 = (const float*)d_in[8];
    float* out = (float*)d_out;

    char* ws = (char*)d_ws;
    // ws layout (bytes):
    u16* wpIh0 = (u16*)(ws + 0);            //  8,388,608
    u16* wpHh0 = (u16*)(ws + 8388608);      //  8,388,608
    u16* wpIh1 = (u16*)(ws + 16777216);     //  8,388,608
    u16* wpHh1 = (u16*)(ws + 25165824);     //  8,388,608
    u16* xpack = (u16*)(ws + 33554432);     // 33,554,432 (1024 tiles x 32KB)
    u16* hist0 = (u16*)(ws + 67108864);     // 33,587,200 (1025 slots x 32KB)
    u16* hist1 = (u16*)(ws + 100696064);    //     65,536 (2 slots ping-pong)
    u16* gxbuf = (u16*)(ws + 100761600);    // 134,217,728
    unsigned* flags = (unsigned*)(ws + 234979328); // 262,400 -> total ~235.3 MiB

    init_zero<<<dim3(64), dim3(256), 0, stream>>>(flags, (unsigned*)hist0, (unsigned*)hist1);

    pack_tiles<<<dim3(256), dim3(256), 0, stream>>>(Wih0, wpIh0, 1);
    pack_tiles<<<dim3(256), dim3(256), 0, stream>>>(Whh0, wpHh0, 1);
    pack_tiles<<<dim3(256), dim3(256), 0, stream>>>(Wih1, wpIh1, 1);
    pack_tiles<<<dim3(256), dim3(256), 0, stream>>>(Whh1, wpHh1, 1);
    pack_tiles<<<dim3(1024), dim3(256), 0, stream>>>(x, xpack, 0);

    // layer 0: gx = x @ Wih0^T + bih0 + bhh0 ; scan (full h history kept)
    gx_gemm<<<dim3(64, TQ), dim3(256), 0, stream>>>(
        (const bf16x8*)xpack, (const bf16x8*)wpIh0, bih0, bhh0, gxbuf);
    lstm_scan<<<dim3(NBLK), dim3(256), 0, stream>>>(
        gxbuf, (const bf16x8*)wpHh0, (unsigned*)hist0, flags, 1u, 0x7fffffff,
        (float*)nullptr, out + 16777216, out + 16777216 + 32768);

    // layer 1: gx = out0 @ Wih1^T + biases ; scan (ping-pong h, writes out1)
    gx_gemm<<<dim3(64, TQ), dim3(256), 0, stream>>>(
        ((const bf16x8*)hist0) + 2048, (const bf16x8*)wpIh1, bih1, bhh1, gxbuf);
    lstm_scan<<<dim3(NBLK), dim3(256), 0, stream>>>(
        gxbuf, (const bf16x8*)wpHh1, (unsigned*)hist1, flags, 2u, 1,
        out, out + 16777216 + 16384, out + 16777216 + 32768 + 16384);
}

// Round 5
// 6929.091 us; speedup vs baseline: 4.3072x; 1.5506x over previous
//
#include <hip/hip_runtime.h>

// LSTM T=1024 B=16 I=H=1024 L=2. f32 in/out, bf16 MFMA internally.
// Round 5: both layers pipelined in ONE 128-block persistent kernel,
// skew = 1 step. Layer-1 fuses its input projection (A = out0(t), already
// A-frag-packed in hist0) with its recurrence GEMM. Cross-block data moves
// via relaxed agent-scope atomics (coherent LLC, no cache flushes).

#define T_STEPS 1024
#define TQ 16        // t-chunks for gx gemm grid

typedef unsigned short u16;
typedef unsigned long long u64;
typedef __attribute__((ext_vector_type(8))) __bf16 bf16x8;      // 8 bf16 = 4 VGPR
typedef __attribute__((ext_vector_type(4))) float float4v;      // MFMA C/D + f32 loads
typedef __attribute__((ext_vector_type(4))) unsigned short ushort4v;
typedef __attribute__((ext_vector_type(8))) unsigned short ushort8;

__device__ __forceinline__ float bf2f(u16 h) {
    unsigned u = ((unsigned)h) << 16;
    return __builtin_bit_cast(float, u);
}
__device__ __forceinline__ u16 f2bf(float f) {
    unsigned u = __builtin_bit_cast(unsigned, f);
    u += 0x7fff + ((u >> 16) & 1);   // RNE
    return (u16)(u >> 16);
}

__device__ __forceinline__ float4v mfma16(bf16x8 a, bf16x8 b, float4v c) {
    return __builtin_amdgcn_mfma_f32_16x16x32_bf16(a, b, c, 0, 0, 0);
}
__device__ __forceinline__ unsigned aload(const unsigned* p) {
    return __hip_atomic_load(p, __ATOMIC_RELAXED, __HIP_MEMORY_SCOPE_AGENT);
}
__device__ __forceinline__ u64 aload64(const u64* p) {
    return __hip_atomic_load(p, __ATOMIC_RELAXED, __HIP_MEMORY_SCOPE_AGENT);
}
__device__ __forceinline__ void astore(unsigned* p, unsigned v) {
    __hip_atomic_store(p, v, __ATOMIC_RELAXED, __HIP_MEMORY_SCOPE_AGENT);
}

// ---------------------------------------------------------------- init
__global__ void init_zero(unsigned* __restrict__ flags0,  // 1025*64
                          unsigned* __restrict__ flags1,  // 4*64 ring
                          unsigned* __restrict__ h0,      // 8192  (hist0 slot 0)
                          unsigned* __restrict__ h1) {    // 16384 (hist1 both slots)
    int i = blockIdx.x * 256 + threadIdx.x;
    const int N0 = 65600, N1 = 256, N2 = 8192, N3 = 16384;
    for (int k = i; k < N0 + N1 + N2 + N3; k += 64 * 256) {
        if (k < N0) flags0[k] = 0u;
        else if (k < N0 + N1) flags1[k - N0] = 0u;
        else if (k < N0 + N1 + N2) h0[k - N0 - N1] = 0u;
        else h1[k - N0 - N1 - N2] = 0u;
    }
}

// ---------------------------------------------------------------- pack
// f32 -> bf16 A/B-frag tiles. dst[tile][kc][lane][8] =
//   src[rowbase+lane%16][kc*32+(lane/16)*8+j]
__device__ __forceinline__ void pack_one(const float* src, u16* dst, int tile, int rowbase) {
    int tid = threadIdx.x;
    ushort8* d = (ushort8*)dst;
#pragma unroll
    for (int it = 0; it < 8; ++it) {
        int c = tid + it * 256;
        int kc = c >> 6, lane = c & 63;
        const float4v* s4 = (const float4v*)(src + (((long)(rowbase + (lane & 15))) << 10)
                                                 + (kc << 5) + ((lane >> 4) << 3));
        float4v lo = s4[0], hi = s4[1];
        ushort8 o;
        o[0] = f2bf(lo[0]); o[1] = f2bf(lo[1]); o[2] = f2bf(lo[2]); o[3] = f2bf(lo[3]);
        o[4] = f2bf(hi[0]); o[5] = f2bf(hi[1]); o[6] = f2bf(hi[2]); o[7] = f2bf(hi[3]);
        d[tile * 2048 + c] = o;
    }
}

__global__ void pack_x(const float* __restrict__ src, u16* __restrict__ dst) {
    pack_one(src, dst, blockIdx.x, blockIdx.x << 4);   // rowbase = t*16
}

// 4 weight matrices in one dispatch: grid 1024, which = blockIdx>>8
__global__ void pack_w(const float* __restrict__ w0, const float* __restrict__ w1,
                       const float* __restrict__ w2, const float* __restrict__ w3,
                       u16* __restrict__ d0, u16* __restrict__ d1,
                       u16* __restrict__ d2, u16* __restrict__ d3) {
    int which = blockIdx.x >> 8, tile = blockIdx.x & 255;
    const float* s = (which == 0) ? w0 : (which == 1) ? w1 : (which == 2) ? w2 : w3;
    u16* d = (which == 0) ? d0 : (which == 1) ? d1 : (which == 2) ? d2 : d3;
    int rowbase = ((tile & 3) << 10) + ((tile >> 2) << 4);
    pack_one(s, d, tile, rowbase);
}

// ---------------------------------------------------------------- gx gemm (layer 0)
__global__ __launch_bounds__(256, 1) void gx_gemm(
        const bf16x8* __restrict__ ap, const bf16x8* __restrict__ wp,
        const float* __restrict__ bih, const float* __restrict__ bhh,
        u16* __restrict__ gx) {
    int blk = blockIdx.x, tq = blockIdx.y;
    int tid = threadIdx.x, w = tid >> 6, L = tid & 63;
    int td = blk * 4 + w;
    int gc = (w << 10) + (blk << 4) + (L & 15);
    float bsum = bih[gc] + bhh[gc];

    bf16x8 wf[32];
    const bf16x8* wpt = wp + td * 2048;
#pragma unroll
    for (int kc = 0; kc < 32; ++kc) wf[kc] = wpt[kc * 64 + L];

    const int tch = T_STEPS / TQ;
    for (int tt = 0; tt < tch; ++tt) {
        int t = tq * tch + tt;
        const bf16x8* at = ap + t * 2048;
        float4v a0 = {0.f, 0.f, 0.f, 0.f}, a1 = {0.f, 0.f, 0.f, 0.f};
#pragma unroll
        for (int kc = 0; kc < 16; ++kc) {
            a0 = mfma16(at[(2 * kc) * 64 + L], wf[2 * kc], a0);
            a1 = mfma16(at[(2 * kc + 1) * 64 + L], wf[2 * kc + 1], a1);
        }
        ushort4v o;
#pragma unroll
        for (int r = 0; r < 4; ++r) o[r] = f2bf(a0[r] + a1[r] + bsum);
        ((ushort4v*)gx)[((t * 64 + blk) * 4 + w) * 64 + L] = o;
    }
}

// ---------------------------------------------------------------- fused pipelined scan
__global__ __launch_bounds__(256, 1) void lstm_scan2(
        const u16* __restrict__ gx0,     // layer-0 gates_x (C-frag, both biases)
        const bf16x8* __restrict__ wpHh0,
        const bf16x8* __restrict__ wpIh1, const bf16x8* __restrict__ wpHh1,
        const float* __restrict__ bih1, const float* __restrict__ bhh1,
        unsigned* hist0w,                // 1025 slots x 8192 u32 (A-frag h0)
        unsigned* hist1w,                // 2 slots ping-pong (A-frag h1)
        unsigned* flags0,                // [1025][64] 0/1
        unsigned* flags1,                // [4][64] ring, tag = step
        float* outbase) {                // d_out
    __shared__ u64 hbufA[4096];          // 32 KB
    __shared__ u64 hbufB[4096];          // 32 KB (layer-1 only)
    __shared__ float4v lds_g[4][64];

    int tid = threadIdx.x, w = tid >> 6, L = tid & 63;
    int m = tid >> 4, j = tid & 15;
    int Lc = ((m >> 2) << 4) | j, rr = m & 3;
    int layer = (blockIdx.x >= 64);
    int blk = blockIdx.x & 63;
    int hcol = (blk << 4) + j;
    int kcw = hcol >> 5, laneg = (hcol >> 3) & 3, jj = hcol & 7;
    int hwoff32 = ((kcw * 64 + m + (laneg << 4)) << 2) + (jj >> 1);
    float* fH = outbase + 16777216 + (layer ? 16384 : 0);
    float* fC = outbase + 16777216 + 32768 + (layer ? 16384 : 0);
    float c = 0.f;

    if (!layer) {
        // ---------------- layer 0 (round-4 proven body) ----------------
        bf16x8 wf[32];
        const bf16x8* wpt = wpHh0 + (blk * 4 + w) * 2048;
#pragma unroll
        for (int kc = 0; kc < 32; ++kc) wf[kc] = wpt[kc * 64 + L];
        const bf16x8* hp = (const bf16x8*)hbufA;

        for (int t = 0; t < T_STEPS; ++t) {
            ushort4v gxv = ((const ushort4v*)gx0)[((t * 64 + blk) * 4 + w) * 64 + L];
            if (t > 0) {
                if (tid < 64) {
                    unsigned v;
                    do { v = aload(&flags0[t * 64 + tid]); }
                    while (__ballot(v != 0u) != ~0ull);
                }
                __syncthreads();
            }
            {   // stage h0(t) slot -> LDS
                const u64* hsrc = (const u64*)hist0w + (size_t)t * 4096;
                u64 tmp[16];
#pragma unroll
                for (int i = 0; i < 16; ++i) tmp[i] = aload64(hsrc + (i << 8) + tid);
#pragma unroll
                for (int i = 0; i < 16; ++i) hbufA[(i << 8) + tid] = tmp[i];
            }
            __syncthreads();

            float4v a0 = {0.f, 0.f, 0.f, 0.f}, a1 = {0.f, 0.f, 0.f, 0.f};
#pragma unroll
            for (int kc = 0; kc < 16; ++kc) {
                a0 = mfma16(hp[(2 * kc) * 64 + L], wf[2 * kc], a0);
                a1 = mfma16(hp[(2 * kc + 1) * 64 + L], wf[2 * kc + 1], a1);
            }
            float4v g4;
#pragma unroll
            for (int r = 0; r < 4; ++r) g4[r] = a0[r] + a1[r] + bf2f(gxv[r]);
            lds_g[w][L] = g4;
            __syncthreads();

            float gi = lds_g[0][Lc][rr], gf = lds_g[1][Lc][rr];
            float gg = lds_g[2][Lc][rr], go = lds_g[3][Lc][rr];
            float iv = 1.f / (1.f + __expf(-gi));
            float fv = 1.f / (1.f + __expf(-gf));
            float gv = 1.f - 2.f / (1.f + __expf(2.f * gg));
            float ov = 1.f / (1.f + __expf(-go));
            c = fv * c + iv * gv;
            float h = ov * (1.f - 2.f / (1.f + __expf(2.f * c)));
            unsigned hb = f2bf(h);

            unsigned other = (unsigned)__shfl_xor((int)hb, 1);
            if (!(tid & 1))
                astore(hist0w + (size_t)(t + 1) * 8192 + hwoff32, hb | (other << 16));
            if (t == T_STEPS - 1) {
                fH[(m << 10) + hcol] = h;
                fC[(m << 10) + hcol] = c;
            }
            __builtin_amdgcn_s_waitcnt(0);
            __syncthreads();
            if (tid == 0) astore(&flags0[(t + 1) * 64 + blk], 1u);
        }
    } else {
        // ---------------- layer 1 (fused ih + hh GEMM) ----------------
        bf16x8 wi[32], wh[32];
        const bf16x8* p1 = wpIh1 + (blk * 4 + w) * 2048;
        const bf16x8* p2 = wpHh1 + (blk * 4 + w) * 2048;
#pragma unroll
        for (int kc = 0; kc < 32; ++kc) wi[kc] = p1[kc * 64 + L];
#pragma unroll
        for (int kc = 0; kc < 32; ++kc) wh[kc] = p2[kc * 64 + L];
        int gc = (w << 10) + (blk << 4) + (L & 15);
        float bsum = bih1[gc] + bhh1[gc];
        const bf16x8* hA = (const bf16x8*)hbufA;   // out0(t) = h0(t+1)
        const bf16x8* hB = (const bf16x8*)hbufB;   // h1(t)

        for (int t = 0; t < T_STEPS; ++t) {
            if (tid < 64) {
                unsigned v0, v1;
                do {
                    v0 = aload(&flags0[(t + 1) * 64 + tid]);
                    v1 = (t > 0) ? aload(&flags1[(t & 3) * 64 + tid]) : (unsigned)t;
                } while (__ballot(v0 != 0u && v1 == (unsigned)t) != ~0ull);
            }
            __syncthreads();
            {   // stage out0(t) and h1(t) -> LDS
                const u64* sa = (const u64*)hist0w + (size_t)(t + 1) * 4096;
                const u64* sb = (const u64*)hist1w + (size_t)(t & 1) * 4096;
                u64 ta[16], tb[16];
#pragma unroll
                for (int i = 0; i < 16; ++i) ta[i] = aload64(sa + (i << 8) + tid);
#pragma unroll
                for (int i = 0; i < 16; ++i) tb[i] = aload64(sb + (i << 8) + tid);
#pragma unroll
                for (int i = 0; i < 16; ++i) hbufA[(i << 8) + tid] = ta[i];
#pragma unroll
                for (int i = 0; i < 16; ++i) hbufB[(i << 8) + tid] = tb[i];
            }
            __syncthreads();

            float4v a0 = {0.f, 0.f, 0.f, 0.f}, a1 = {0.f, 0.f, 0.f, 0.f};
            float4v a2 = {0.f, 0.f, 0.f, 0.f}, a3 = {0.f, 0.f, 0.f, 0.f};
#pragma unroll
            for (int kc = 0; kc < 16; ++kc) {
                a0 = mfma16(hA[(2 * kc) * 64 + L], wi[2 * kc], a0);
                a1 = mfma16(hA[(2 * kc + 1) * 64 + L], wi[2 * kc + 1], a1);
                a2 = mfma16(hB[(2 * kc) * 64 + L], wh[2 * kc], a2);
                a3 = mfma16(hB[(2 * kc + 1) * 64 + L], wh[2 * kc + 1], a3);
            }
            float4v g4;
#pragma unroll
            for (int r = 0; r < 4; ++r) g4[r] = a0[r] + a1[r] + a2[r] + a3[r] + bsum;
            lds_g[w][L] = g4;
            __syncthreads();

            float gi = lds_g[0][Lc][rr], gf = lds_g[1][Lc][rr];
            float gg = lds_g[2][Lc][rr], go = lds_g[3][Lc][rr];
            float iv = 1.f / (1.f + __expf(-gi));
            float fv = 1.f / (1.f + __expf(-gf));
            float gv = 1.f - 2.f / (1.f + __expf(2.f * gg));
            float ov = 1.f / (1.f + __expf(-go));
            c = fv * c + iv * gv;
            float h = ov * (1.f - 2.f / (1.f + __expf(2.f * c)));
            unsigned hb = f2bf(h);

            unsigned other = (unsigned)__shfl_xor((int)hb, 1);
            if (!(tid & 1))
                astore(hist1w + (size_t)((t + 1) & 1) * 8192 + hwoff32, hb | (other << 16));
            outbase[(t << 14) + (m << 10) + hcol] = h;
            if (t == T_STEPS - 1) {
                fH[(m << 10) + hcol] = h;
                fC[(m << 10) + hcol] = c;
            }
            __builtin_amdgcn_s_waitcnt(0);
            __syncthreads();
            if (tid == 0) astore(&flags1[(((t + 1) & 3) << 6) + blk], (unsigned)(t + 1));
        }
    }
}

// ---------------------------------------------------------------- launch
extern "C" void kernel_launch(void* const* d_in, const int* in_sizes, int n_in,
                              void* d_out, int out_size, void* d_ws, size_t ws_size,
                              hipStream_t stream) {
    const float* x    = (const float*)d_in[0];
    const float* Wih0 = (const float*)d_in[1];
    const float* bih0 = (const float*)d_in[2];
    const float* Whh0 = (const float*)d_in[3];
    const float* bhh0 = (const float*)d_in[4];
    const float* Wih1 = (const float*)d_in[5];
    const float* bih1 = (const float*)d_in[6];
    const float* Whh1 = (const float*)d_in[7];
    const float* bhh1 = (const float*)d_in[8];
    float* out = (float*)d_out;

    char* ws = (char*)d_ws;
    u16* wpIh0 = (u16*)(ws + 0);            //  8,388,608
    u16* wpHh0 = (u16*)(ws + 8388608);      //  8,388,608
    u16* wpIh1 = (u16*)(ws + 16777216);     //  8,388,608
    u16* wpHh1 = (u16*)(ws + 25165824);     //  8,388,608
    u16* xpack = (u16*)(ws + 33554432);     // 33,554,432
    u16* hist0 = (u16*)(ws + 67108864);     // 33,587,200 (1025 x 32KB)
    u16* hist1 = (u16*)(ws + 100696064);    //     65,536 (2 x 32KB)
    u16* gxbuf = (u16*)(ws + 100761600);    // 134,217,728
    unsigned* flags0 = (unsigned*)(ws + 234979328); // 262,400
    unsigned* flags1 = (unsigned*)(ws + 235241728); //   1,024  -> 235,242,752 total

    init_zero<<<dim3(64), dim3(256), 0, stream>>>(flags0, flags1,
                                                  (unsigned*)hist0, (unsigned*)hist1);
    pack_w<<<dim3(1024), dim3(256), 0, stream>>>(Wih0, Whh0, Wih1, Whh1,
                                                 wpIh0, wpHh0, wpIh1, wpHh1);
    pack_x<<<dim3(1024), dim3(256), 0, stream>>>(x, xpack);
    gx_gemm<<<dim3(64, TQ), dim3(256), 0, stream>>>(
        (const bf16x8*)xpack, (const bf16x8*)wpIh0, bih0, bhh0, gxbuf);
    lstm_scan2<<<dim3(128), dim3(256), 0, stream>>>(
        gxbuf, (const bf16x8*)wpHh0, (const bf16x8*)wpIh1, (const bf16x8*)wpHh1,
        bih1, bhh1, (unsigned*)hist0, (unsigned*)hist1, flags0, flags1, out);
}